// Round 2
// baseline (3175.726 us; speedup 1.0000x reference)
//
#include <hip/hip_runtime.h>
#include <hip/hip_bf16.h>

#define D 128

__device__ __forceinline__ float bf2f(unsigned short u) {
    union { unsigned int i; float f; } c;
    c.i = ((unsigned int)u) << 16;
    return c.f;
}

__device__ __forceinline__ unsigned short f2bf(float f) {
    __hip_bfloat16 h = __float2bfloat16(f);
    return *(unsigned short*)&h;
}

// Probe: decide (a) is x fp32 or bf16, (b) is edge_index int64 or int32.
// flags[0] = 1 if x is fp32;  flags[1] = 1 if edge_index is int64.
__global__ void probe_kernel(const unsigned short* __restrict__ x,
                             const long long* __restrict__ ei64,
                             int nNodes, int* __restrict__ flags)
{
    if (blockIdx.x != 0 || threadIdx.x != 0) return;
    // bf16 N(0,1) data: every ushort decodes to |v| < ~10.
    // fp32 data read as bf16: low halves are mantissa garbage -> huge/NaN often.
    int cnt = 0;
    for (int i = 0; i < 512; ++i) {
        float v = bf2f(x[i]);
        if (!(fabsf(v) < 1e4f)) cnt++;   // NaN also counts (comparison false)
    }
    flags[0] = (cnt > 8) ? 1 : 0;
    // int64 indices: all in [0, nNodes). int32 data read as int64: >= 2^32 w.h.p.
    int bad = 0;
    for (int i = 0; i < 64; ++i) {
        long long v = ei64[i];
        if (v < 0 || v >= (long long)nNodes) bad++;
    }
    flags[1] = (bad == 0) ? 1 : 0;
}

// Scatter: one edge per 32 threads, 4 elements per thread.
__global__ __launch_bounds__(256) void scatter_kernel(
    const void* __restrict__ xv,
    const void* __restrict__ eiv,
    float* __restrict__ agg,
    int nEdges,
    const int* __restrict__ flags)
{
    long long tid = (long long)blockIdx.x * 256 + threadIdx.x;
    int e = (int)(tid >> 5);
    if (e >= nEdges) return;
    int q = (int)tid & 31;            // which group of 4 elements

    const int xf32 = flags[0];
    const int i64  = flags[1];

    int s, d;
    if (i64) {
        const long long* ei = (const long long*)eiv;
        s = (int)ei[e];
        d = (int)ei[(size_t)nEdges + e];
    } else {
        const int* ei = (const int*)eiv;
        s = ei[e];
        d = ei[(size_t)nEdges + e];
    }

    float4 v;
    if (xf32) {
        v = ((const float4*)xv)[(size_t)s * 32 + q];
    } else {
        ushort4 u = ((const ushort4*)xv)[(size_t)s * 32 + q];
        v.x = bf2f(u.x); v.y = bf2f(u.y); v.z = bf2f(u.z); v.w = bf2f(u.w);
    }

    float* ap = agg + (size_t)d * D + q * 4;
    atomicAdd(ap + 0, v.x);
    atomicAdd(ap + 1, v.y);
    atomicAdd(ap + 2, v.z);
    atomicAdd(ap + 3, v.w);
}

// GEMM: out[n][:] = cast( agg[n][:] @ W + b ), W staged fp32 in LDS.
__global__ __launch_bounds__(256) void gemm_kernel(
    const float* __restrict__ agg,
    const void* __restrict__ Wv,
    const void* __restrict__ bv,
    void* __restrict__ outv,
    int nNodes,
    const int* __restrict__ flags)
{
    __shared__ float Ws[D * D];   // 64 KB
    __shared__ float bs[D];

    const int xf32 = flags[0];

    if (xf32) {
        const float* W = (const float*)Wv;
        for (int i = threadIdx.x; i < D * D; i += 256) Ws[i] = W[i];
        if (threadIdx.x < D) bs[threadIdx.x] = ((const float*)bv)[threadIdx.x];
    } else {
        const unsigned short* W = (const unsigned short*)Wv;
        for (int i = threadIdx.x; i < D * D; i += 256) Ws[i] = bf2f(W[i]);
        if (threadIdx.x < D) bs[threadIdx.x] = bf2f(((const unsigned short*)bv)[threadIdx.x]);
    }
    __syncthreads();

    const int lane = threadIdx.x & 31;   // group of 4 output columns
    const int rgrp = threadIdx.x >> 5;   // row within block pass (0..7)
    const int c = lane * 4;

    for (int row = blockIdx.x * 8 + rgrp; row < nNodes; row += gridDim.x * 8) {
        const float* ar = agg + (size_t)row * D;
        float4 acc = { bs[c], bs[c + 1], bs[c + 2], bs[c + 3] };

        #pragma unroll
        for (int k = 0; k < D; k += 4) {
            float4 a = *(const float4*)(ar + k);
            float4 w0 = *(const float4*)&Ws[(k + 0) * D + c];
            float4 w1 = *(const float4*)&Ws[(k + 1) * D + c];
            float4 w2 = *(const float4*)&Ws[(k + 2) * D + c];
            float4 w3 = *(const float4*)&Ws[(k + 3) * D + c];
            acc.x += a.x * w0.x; acc.y += a.x * w0.y; acc.z += a.x * w0.z; acc.w += a.x * w0.w;
            acc.x += a.y * w1.x; acc.y += a.y * w1.y; acc.z += a.y * w1.z; acc.w += a.y * w1.w;
            acc.x += a.z * w2.x; acc.y += a.z * w2.y; acc.z += a.z * w2.z; acc.w += a.z * w2.w;
            acc.x += a.w * w3.x; acc.y += a.w * w3.y; acc.z += a.w * w3.z; acc.w += a.w * w3.w;
        }

        if (xf32) {
            ((float4*)outv)[(size_t)row * 32 + lane] = acc;
        } else {
            ushort4 o;
            o.x = f2bf(acc.x); o.y = f2bf(acc.y); o.z = f2bf(acc.z); o.w = f2bf(acc.w);
            ((ushort4*)outv)[(size_t)row * 32 + lane] = o;
        }
    }
}

extern "C" void kernel_launch(void* const* d_in, const int* in_sizes, int n_in,
                              void* d_out, int out_size, void* d_ws, size_t ws_size,
                              hipStream_t stream) {
    const void* x  = d_in[0];   // (N, 128)  fp32 or bf16 (probed)
    const void* ei = d_in[1];   // (2, E)    int64 or int32 (probed)
    const void* W  = d_in[2];   // (128, 128)
    const void* b  = d_in[3];   // (128,)

    const int nNodes = in_sizes[0] / D;
    const int nEdges = in_sizes[1] / 2;

    // ws layout: [0,512)  flags;  [512, 512 + N*128*4)  fp32 agg
    int*   flags = (int*)d_ws;
    float* agg   = (float*)((char*)d_ws + 512);

    probe_kernel<<<1, 64, 0, stream>>>((const unsigned short*)x, (const long long*)ei,
                                       nNodes, flags);

    hipMemsetAsync(agg, 0, (size_t)nNodes * D * sizeof(float), stream);

    long long total = (long long)nEdges * 32;
    int blocks = (int)((total + 255) / 256);
    scatter_kernel<<<blocks, 256, 0, stream>>>(x, ei, agg, nEdges, flags);

    int gblocks = (nNodes + 7) / 8;
    gemm_kernel<<<gblocks, 256, 0, stream>>>(agg, W, b, d_out, nNodes, flags);
}

// Round 3
// 749.217 us; speedup vs baseline: 4.2387x; 4.2387x over previous
//
#include <hip/hip_runtime.h>
#include <hip/hip_bf16.h>

#define D 128

__device__ __forceinline__ float bf2f(unsigned short u) {
    union { unsigned int i; float f; } c;
    c.i = ((unsigned int)u) << 16;
    return c.f;
}
__device__ __forceinline__ float bits2f(unsigned int i) {
    union { unsigned int i; float f; } c;
    c.i = i;
    return c.f;
}
__device__ __forceinline__ unsigned short f2bf(float f) {
    __hip_bfloat16 h = __float2bfloat16(f);
    return *(unsigned short*)&h;
}

// Probe dtypes at runtime. flags[0]=1 if x is fp32; flags[1]=1 if edge_index is int64.
__global__ void probe_kernel(const unsigned short* __restrict__ x,
                             const long long* __restrict__ ei64,
                             int nNodes, int* __restrict__ flags)
{
    if (blockIdx.x != 0 || threadIdx.x != 0) return;
    int cnt = 0;
    for (int i = 0; i < 512; ++i) {
        float v = bf2f(x[i]);
        if (!(fabsf(v) < 1e4f)) cnt++;   // NaN counts too
    }
    flags[0] = (cnt > 8) ? 1 : 0;
    int bad = 0;
    for (int i = 0; i < 64; ++i) {
        long long v = ei64[i];
        if (v < 0 || v >= (long long)nNodes) bad++;
    }
    flags[1] = (bad == 0) ? 1 : 0;
}

// ---------- CSR build ----------
__global__ __launch_bounds__(256) void count_kernel(
    const void* __restrict__ eiv, int* __restrict__ cnt, int nEdges,
    const int* __restrict__ flags)
{
    int e = blockIdx.x * 256 + threadIdx.x;
    if (e >= nEdges) return;
    int d;
    if (flags[1]) d = (int)((const long long*)eiv)[(size_t)nEdges + e];
    else          d = ((const int*)eiv)[(size_t)nEdges + e];
    atomicAdd(&cnt[d], 1);
}

// Single-block exclusive scan: starts[0..N] (starts[N]=E), cursors[i]=starts[i].
__global__ __launch_bounds__(1024) void scan_kernel(
    const int* __restrict__ cnt, int* __restrict__ starts,
    int* __restrict__ cursors, int N)
{
    __shared__ int bufA[1024];
    __shared__ int bufB[1024];
    const int t = threadIdx.x;
    const int chunk = (N + 1023) / 1024;
    const int lo = t * chunk;
    const int hi = min(lo + chunk, N);

    int s = 0;
    for (int i = lo; i < hi; ++i) s += cnt[i];
    bufA[t] = s;
    __syncthreads();

    int* in = bufA;
    int* out = bufB;
    for (int step = 1; step < 1024; step <<= 1) {
        int v = in[t];
        if (t >= step) v += in[t - step];
        out[t] = v;
        __syncthreads();
        int* tmp = in; in = out; out = tmp;
    }
    int incl = in[t];          // inclusive scan of per-thread sums
    int off = incl - s;        // exclusive offset for this thread's chunk

    for (int i = lo; i < hi; ++i) {
        int c = cnt[i];
        starts[i] = off;
        cursors[i] = off;
        off += c;
    }
    if (t == 1023) starts[N] = off;   // == nEdges
}

__global__ __launch_bounds__(256) void fill_kernel(
    const void* __restrict__ eiv, int* __restrict__ cursors,
    int* __restrict__ bucket, int nEdges, const int* __restrict__ flags)
{
    int e = blockIdx.x * 256 + threadIdx.x;
    if (e >= nEdges) return;
    int s, d;
    if (flags[1]) {
        const long long* ei = (const long long*)eiv;
        s = (int)ei[e];
        d = (int)ei[(size_t)nEdges + e];
    } else {
        const int* ei = (const int*)eiv;
        s = ei[e];
        d = ei[(size_t)nEdges + e];
    }
    int pos = atomicAdd(&cursors[d], 1);
    bucket[pos] = s;
}

// ---------- gather (no atomics): one wave per node ----------
__global__ __launch_bounds__(256) void gather_kernel(
    const void* __restrict__ xv, const int* __restrict__ starts,
    const int* __restrict__ bucket, float* __restrict__ agg,
    int nNodes, const int* __restrict__ flags)
{
    int wave = blockIdx.x * 4 + (threadIdx.x >> 6);
    if (wave >= nNodes) return;
    const int lane = threadIdx.x & 63;
    const int xf32 = flags[0];

    const int beg = starts[wave];
    const int end = starts[wave + 1];

    float ax = 0.f, ay = 0.f;
    if (xf32) {
        const float2* x2 = (const float2*)xv;
        for (int i = beg; i < end; ++i) {
            int s = bucket[i];
            float2 v = x2[(size_t)s * 64 + lane];
            ax += v.x; ay += v.y;
        }
    } else {
        const unsigned int* xu = (const unsigned int*)xv;
        for (int i = beg; i < end; ++i) {
            int s = bucket[i];
            unsigned int u = xu[(size_t)s * 64 + lane];
            ax += bits2f(u << 16);
            ay += bits2f(u & 0xFFFF0000u);
        }
    }
    float2 o; o.x = ax; o.y = ay;
    ((float2*)agg)[(size_t)wave * 64 + lane] = o;
}

// ---------- fallback scatter (atomics) if ws too small for CSR ----------
__global__ __launch_bounds__(256) void scatter_kernel(
    const void* __restrict__ xv, const void* __restrict__ eiv,
    float* __restrict__ agg, int nEdges, const int* __restrict__ flags)
{
    long long tid = (long long)blockIdx.x * 256 + threadIdx.x;
    int e = (int)(tid >> 5);
    if (e >= nEdges) return;
    int q = (int)tid & 31;

    const int xf32 = flags[0];
    const int i64  = flags[1];
    int s, d;
    if (i64) {
        const long long* ei = (const long long*)eiv;
        s = (int)ei[e]; d = (int)ei[(size_t)nEdges + e];
    } else {
        const int* ei = (const int*)eiv;
        s = ei[e]; d = ei[(size_t)nEdges + e];
    }
    float4 v;
    if (xf32) {
        v = ((const float4*)xv)[(size_t)s * 32 + q];
    } else {
        ushort4 u = ((const ushort4*)xv)[(size_t)s * 32 + q];
        v.x = bf2f(u.x); v.y = bf2f(u.y); v.z = bf2f(u.z); v.w = bf2f(u.w);
    }
    float* ap = agg + (size_t)d * D + q * 4;
    atomicAdd(ap + 0, v.x);
    atomicAdd(ap + 1, v.y);
    atomicAdd(ap + 2, v.z);
    atomicAdd(ap + 3, v.w);
}

// ---------- register-blocked GEMM: out = cast(agg @ W + b) ----------
// 64-row tile per block; thread = 8 rows x 4 cols (32 accs); W fp32 in LDS.
__global__ __launch_bounds__(256) void gemm_kernel(
    const float* __restrict__ agg, const void* __restrict__ Wv,
    const void* __restrict__ bv, void* __restrict__ outv,
    int nNodes, const int* __restrict__ flags)
{
    __shared__ float Ws[D * D];   // 64 KB
    __shared__ float bs[D];

    const int xf32 = flags[0];
    if (xf32) {
        const float* W = (const float*)Wv;
        for (int i = threadIdx.x; i < D * D; i += 256) Ws[i] = W[i];
        if (threadIdx.x < D) bs[threadIdx.x] = ((const float*)bv)[threadIdx.x];
    } else {
        const unsigned short* W = (const unsigned short*)Wv;
        for (int i = threadIdx.x; i < D * D; i += 256) Ws[i] = bf2f(W[i]);
        if (threadIdx.x < D) bs[threadIdx.x] = bf2f(((const unsigned short*)bv)[threadIdx.x]);
    }
    __syncthreads();

    const int cg = threadIdx.x & 31;   // col group (4 cols)
    const int rg = threadIdx.x >> 5;   // row group (8 rows)
    const int c = cg * 4;
    const int row0 = blockIdx.x * 64 + rg * 8;

    const float* ap[8];
    #pragma unroll
    for (int r = 0; r < 8; ++r) {
        int row = row0 + r;
        ap[r] = agg + (size_t)(row < nNodes ? row : nNodes - 1) * D;
    }

    float4 acc[8];
    #pragma unroll
    for (int r = 0; r < 8; ++r)
        acc[r] = make_float4(bs[c], bs[c + 1], bs[c + 2], bs[c + 3]);

    for (int k = 0; k < D; k += 4) {
        float4 w0 = *(const float4*)&Ws[(k + 0) * D + c];
        float4 w1 = *(const float4*)&Ws[(k + 1) * D + c];
        float4 w2 = *(const float4*)&Ws[(k + 2) * D + c];
        float4 w3 = *(const float4*)&Ws[(k + 3) * D + c];
        #pragma unroll
        for (int r = 0; r < 8; ++r) {
            float4 a = *(const float4*)(ap[r] + k);
            acc[r].x += a.x * w0.x + a.y * w1.x + a.z * w2.x + a.w * w3.x;
            acc[r].y += a.x * w0.y + a.y * w1.y + a.z * w2.y + a.w * w3.y;
            acc[r].z += a.x * w0.z + a.y * w1.z + a.z * w2.z + a.w * w3.z;
            acc[r].w += a.x * w0.w + a.y * w1.w + a.z * w2.w + a.w * w3.w;
        }
    }

    #pragma unroll
    for (int r = 0; r < 8; ++r) {
        int row = row0 + r;
        if (row >= nNodes) break;
        if (xf32) {
            ((float4*)outv)[(size_t)row * 32 + cg] = acc[r];
        } else {
            ushort4 o;
            o.x = f2bf(acc[r].x); o.y = f2bf(acc[r].y);
            o.z = f2bf(acc[r].z); o.w = f2bf(acc[r].w);
            ((ushort4*)outv)[(size_t)row * 32 + cg] = o;
        }
    }
}

static inline size_t alignup(size_t v, size_t a) { return (v + a - 1) & ~(a - 1); }

extern "C" void kernel_launch(void* const* d_in, const int* in_sizes, int n_in,
                              void* d_out, int out_size, void* d_ws, size_t ws_size,
                              hipStream_t stream) {
    const void* x  = d_in[0];
    const void* ei = d_in[1];
    const void* W  = d_in[2];
    const void* b  = d_in[3];

    const int nNodes = in_sizes[0] / D;
    const int nEdges = in_sizes[1] / 2;

    // ws layout (fast path): flags | starts[N+1] | cursors[N] | bucket[E] | agg[N*D]
    size_t off_starts  = 512;
    size_t off_cursors = alignup(off_starts + 4ull * (nNodes + 1), 256);
    size_t off_bucket  = alignup(off_cursors + 4ull * nNodes, 256);
    size_t off_agg     = alignup(off_bucket + 4ull * nEdges, 512);
    size_t need_fast   = off_agg + (size_t)nNodes * D * sizeof(float);

    int* flags = (int*)d_ws;
    probe_kernel<<<1, 64, 0, stream>>>((const unsigned short*)x, (const long long*)ei,
                                       nNodes, flags);

    const int eblocks = (nEdges + 255) / 256;

    if (ws_size >= need_fast) {
        int*   starts  = (int*)((char*)d_ws + off_starts);
        int*   cursors = (int*)((char*)d_ws + off_cursors);
        int*   bucket  = (int*)((char*)d_ws + off_bucket);
        float* agg     = (float*)((char*)d_ws + off_agg);

        hipMemsetAsync(cursors, 0, 4ull * nNodes, stream);  // counts
        count_kernel<<<eblocks, 256, 0, stream>>>(ei, cursors, nEdges, flags);
        scan_kernel<<<1, 1024, 0, stream>>>(cursors, starts, cursors, nNodes);
        fill_kernel<<<eblocks, 256, 0, stream>>>(ei, cursors, bucket, nEdges, flags);

        int gwaves  = nNodes;                 // one wave per node
        int gblocks = (gwaves + 3) / 4;       // 4 waves per 256-thread block
        gather_kernel<<<gblocks, 256, 0, stream>>>(x, starts, bucket, agg, nNodes, flags);

        int mblocks = (nNodes + 63) / 64;
        gemm_kernel<<<mblocks, 256, 0, stream>>>(agg, W, b, d_out, nNodes, flags);
    } else {
        // fallback: atomic scatter into agg at d_ws+512
        float* agg = (float*)((char*)d_ws + 512);
        hipMemsetAsync(agg, 0, (size_t)nNodes * D * sizeof(float), stream);
        long long total = (long long)nEdges * 32;
        int sblocks = (int)((total + 255) / 256);
        scatter_kernel<<<sblocks, 256, 0, stream>>>(x, ei, agg, nEdges, flags);
        int mblocks = (nNodes + 63) / 64;
        gemm_kernel<<<mblocks, 256, 0, stream>>>(agg, W, b, d_out, nNodes, flags);
    }
}

// Round 4
// 478.045 us; speedup vs baseline: 6.6432x; 1.5673x over previous
//
#include <hip/hip_runtime.h>
#include <hip/hip_bf16.h>

#define D 128

__device__ __forceinline__ float bf2f(unsigned short u) {
    union { unsigned int i; float f; } c;
    c.i = ((unsigned int)u) << 16;
    return c.f;
}
__device__ __forceinline__ float bits2f(unsigned int i) {
    union { unsigned int i; float f; } c;
    c.i = i;
    return c.f;
}
__device__ __forceinline__ unsigned short f2bf(float f) {
    __hip_bfloat16 h = __float2bfloat16(f);
    return *(unsigned short*)&h;
}

// Probe dtypes at runtime (one wave). flags[0]=1 if x is fp32; flags[1]=1 if ei is int64.
__global__ __launch_bounds__(64) void probe_kernel(
    const unsigned short* __restrict__ x,
    const long long* __restrict__ ei64,
    int nNodes, int* __restrict__ flags)
{
    const int lane = threadIdx.x;
    // bf16 N(0,1): no ushort decodes huge. fp32-as-bf16: low halves are garbage.
    int cnt = 0;
    for (int i = lane; i < 512; i += 64) {
        float v = bf2f(x[i]);
        if (!(fabsf(v) < 1e4f)) cnt++;   // NaN counts
    }
    unsigned long long m1 = __ballot(cnt > 0);
    // int64 indices all in [0,N); int32-as-int64 gives >= 2^32 w.h.p.
    long long v = ei64[lane];
    int bad = (v < 0 || v >= (long long)nNodes) ? 1 : 0;
    unsigned long long m2 = __ballot(bad);
    if (lane == 0) {
        flags[0] = (__popcll(m1) > 2) ? 1 : 0;
        flags[1] = (m2 == 0) ? 1 : 0;
    }
}

// ---------- CSR build ----------
__global__ __launch_bounds__(256) void count_kernel(
    const void* __restrict__ eiv, int* __restrict__ cnt, int nEdges,
    const int* __restrict__ flags)
{
    int e = blockIdx.x * 256 + threadIdx.x;
    if (e >= nEdges) return;
    int d;
    if (flags[1]) d = (int)((const long long*)eiv)[(size_t)nEdges + e];
    else          d = ((const int*)eiv)[(size_t)nEdges + e];
    atomicAdd(&cnt[d], 1);
}

// Parallel scan, phase A: block b reduces cnt[b*1024 .. b*1024+1024) -> partials[b]
__global__ __launch_bounds__(256) void scanA_kernel(
    const int* __restrict__ cnt, int* __restrict__ partials, int N)
{
    __shared__ int red[256];
    const int base = blockIdx.x * 1024;
    int s = 0;
    for (int i = threadIdx.x; i < 1024; i += 256) {
        int idx = base + i;
        if (idx < N) s += cnt[idx];
    }
    red[threadIdx.x] = s;
    __syncthreads();
    for (int st = 128; st > 0; st >>= 1) {
        if (threadIdx.x < st) red[threadIdx.x] += red[threadIdx.x + st];
        __syncthreads();
    }
    if (threadIdx.x == 0) partials[blockIdx.x] = red[0];
}

// Phase B: one block, exclusive scan of partials[0..nb) in place. nb <= 1024.
__global__ __launch_bounds__(1024) void scanB_kernel(
    int* __restrict__ partials, int nb)
{
    __shared__ int bufA[1024];
    __shared__ int bufB[1024];
    const int t = threadIdx.x;
    int v = (t < nb) ? partials[t] : 0;
    bufA[t] = v;
    __syncthreads();
    int* in = bufA;
    int* out = bufB;
    for (int step = 1; step < 1024; step <<= 1) {
        int w = in[t];
        if (t >= step) w += in[t - step];
        out[t] = w;
        __syncthreads();
        int* tmp = in; in = out; out = tmp;
    }
    if (t < nb) partials[t] = in[t] - v;   // exclusive
}

// Phase C: block b scans its cnt chunk locally, adds partials[b], writes starts+cursors.
__global__ __launch_bounds__(256) void scanC_kernel(
    const int* __restrict__ cnt, const int* __restrict__ partials,
    int* __restrict__ starts, int* __restrict__ cursors, int N, int nEdges)
{
    __shared__ int bufA[256];
    __shared__ int bufB[256];
    const int t = threadIdx.x;
    const int base = blockIdx.x * 1024 + t * 4;

    int c0 = (base + 0 < N) ? cnt[base + 0] : 0;
    int c1 = (base + 1 < N) ? cnt[base + 1] : 0;
    int c2 = (base + 2 < N) ? cnt[base + 2] : 0;
    int c3 = (base + 3 < N) ? cnt[base + 3] : 0;
    int s = c0 + c1 + c2 + c3;

    bufA[t] = s;
    __syncthreads();
    int* in = bufA;
    int* out = bufB;
    for (int step = 1; step < 256; step <<= 1) {
        int w = in[t];
        if (t >= step) w += in[t - step];
        out[t] = w;
        __syncthreads();
        int* tmp = in; in = out; out = tmp;
    }
    int off = partials[blockIdx.x] + in[t] - s;   // exclusive within grid

    if (base + 0 < N) { starts[base + 0] = off; cursors[base + 0] = off; off += c0; }
    if (base + 1 < N) { starts[base + 1] = off; cursors[base + 1] = off; off += c1; }
    if (base + 2 < N) { starts[base + 2] = off; cursors[base + 2] = off; off += c2; }
    if (base + 3 < N) { starts[base + 3] = off; cursors[base + 3] = off; off += c3; }
    if (blockIdx.x == 0 && t == 0) starts[N] = nEdges;
}

__global__ __launch_bounds__(256) void fill_kernel(
    const void* __restrict__ eiv, int* __restrict__ cursors,
    int* __restrict__ bucket, int nEdges, const int* __restrict__ flags)
{
    int e = blockIdx.x * 256 + threadIdx.x;
    if (e >= nEdges) return;
    int s, d;
    if (flags[1]) {
        const long long* ei = (const long long*)eiv;
        s = (int)ei[e];
        d = (int)ei[(size_t)nEdges + e];
    } else {
        const int* ei = (const int*)eiv;
        s = ei[e];
        d = ei[(size_t)nEdges + e];
    }
    int pos = atomicAdd(&cursors[d], 1);
    bucket[pos] = s;
}

// ---------- gather (no atomics): one wave per node, 4-way unrolled ----------
__global__ __launch_bounds__(256) void gather_kernel(
    const void* __restrict__ xv, const int* __restrict__ starts,
    const int* __restrict__ bucket, float* __restrict__ agg,
    int nNodes, const int* __restrict__ flags)
{
    int wave = blockIdx.x * 4 + (threadIdx.x >> 6);
    if (wave >= nNodes) return;
    const int lane = threadIdx.x & 63;
    const int xf32 = flags[0];

    const int beg = starts[wave];
    const int end = starts[wave + 1];

    float a0x = 0.f, a0y = 0.f, a1x = 0.f, a1y = 0.f;
    float a2x = 0.f, a2y = 0.f, a3x = 0.f, a3y = 0.f;

    int i = beg;
    if (xf32) {
        const float2* x2 = (const float2*)xv;
        for (; i + 4 <= end; i += 4) {
            int s0 = bucket[i + 0], s1 = bucket[i + 1];
            int s2 = bucket[i + 2], s3 = bucket[i + 3];
            float2 v0 = x2[(size_t)s0 * 64 + lane];
            float2 v1 = x2[(size_t)s1 * 64 + lane];
            float2 v2 = x2[(size_t)s2 * 64 + lane];
            float2 v3 = x2[(size_t)s3 * 64 + lane];
            a0x += v0.x; a0y += v0.y;
            a1x += v1.x; a1y += v1.y;
            a2x += v2.x; a2y += v2.y;
            a3x += v3.x; a3y += v3.y;
        }
        for (; i < end; ++i) {
            float2 v = x2[(size_t)bucket[i] * 64 + lane];
            a0x += v.x; a0y += v.y;
        }
    } else {
        const unsigned int* xu = (const unsigned int*)xv;
        for (; i + 4 <= end; i += 4) {
            int s0 = bucket[i + 0], s1 = bucket[i + 1];
            int s2 = bucket[i + 2], s3 = bucket[i + 3];
            unsigned int u0 = xu[(size_t)s0 * 64 + lane];
            unsigned int u1 = xu[(size_t)s1 * 64 + lane];
            unsigned int u2 = xu[(size_t)s2 * 64 + lane];
            unsigned int u3 = xu[(size_t)s3 * 64 + lane];
            a0x += bits2f(u0 << 16); a0y += bits2f(u0 & 0xFFFF0000u);
            a1x += bits2f(u1 << 16); a1y += bits2f(u1 & 0xFFFF0000u);
            a2x += bits2f(u2 << 16); a2y += bits2f(u2 & 0xFFFF0000u);
            a3x += bits2f(u3 << 16); a3y += bits2f(u3 & 0xFFFF0000u);
        }
        for (; i < end; ++i) {
            unsigned int u = xu[(size_t)bucket[i] * 64 + lane];
            a0x += bits2f(u << 16); a0y += bits2f(u & 0xFFFF0000u);
        }
    }
    float2 o;
    o.x = (a0x + a1x) + (a2x + a3x);
    o.y = (a0y + a1y) + (a2y + a3y);
    ((float2*)agg)[(size_t)wave * 64 + lane] = o;
}

// ---------- fallback scatter (atomics) if ws too small for CSR ----------
__global__ __launch_bounds__(256) void scatter_kernel(
    const void* __restrict__ xv, const void* __restrict__ eiv,
    float* __restrict__ agg, int nEdges, const int* __restrict__ flags)
{
    long long tid = (long long)blockIdx.x * 256 + threadIdx.x;
    int e = (int)(tid >> 5);
    if (e >= nEdges) return;
    int q = (int)tid & 31;

    const int xf32 = flags[0];
    int s, d;
    if (flags[1]) {
        const long long* ei = (const long long*)eiv;
        s = (int)ei[e]; d = (int)ei[(size_t)nEdges + e];
    } else {
        const int* ei = (const int*)eiv;
        s = ei[e]; d = ei[(size_t)nEdges + e];
    }
    float4 v;
    if (xf32) {
        v = ((const float4*)xv)[(size_t)s * 32 + q];
    } else {
        ushort4 u = ((const ushort4*)xv)[(size_t)s * 32 + q];
        v.x = bf2f(u.x); v.y = bf2f(u.y); v.z = bf2f(u.z); v.w = bf2f(u.w);
    }
    float* ap = agg + (size_t)d * D + q * 4;
    atomicAdd(ap + 0, v.x);
    atomicAdd(ap + 1, v.y);
    atomicAdd(ap + 2, v.z);
    atomicAdd(ap + 3, v.w);
}

// ---------- register-blocked GEMM: out = cast(agg @ W + b) ----------
__global__ __launch_bounds__(256) void gemm_kernel(
    const float* __restrict__ agg, const void* __restrict__ Wv,
    const void* __restrict__ bv, void* __restrict__ outv,
    int nNodes, const int* __restrict__ flags)
{
    __shared__ float Ws[D * D];   // 64 KB
    __shared__ float bs[D];

    const int xf32 = flags[0];
    if (xf32) {
        const float* W = (const float*)Wv;
        for (int i = threadIdx.x; i < D * D; i += 256) Ws[i] = W[i];
        if (threadIdx.x < D) bs[threadIdx.x] = ((const float*)bv)[threadIdx.x];
    } else {
        const unsigned short* W = (const unsigned short*)Wv;
        for (int i = threadIdx.x; i < D * D; i += 256) Ws[i] = bf2f(W[i]);
        if (threadIdx.x < D) bs[threadIdx.x] = bf2f(((const unsigned short*)bv)[threadIdx.x]);
    }
    __syncthreads();

    const int cg = threadIdx.x & 31;   // col group (4 cols)
    const int rg = threadIdx.x >> 5;   // row group (8 rows)
    const int c = cg * 4;
    const int row0 = blockIdx.x * 64 + rg * 8;

    const float* ap[8];
    #pragma unroll
    for (int r = 0; r < 8; ++r) {
        int row = row0 + r;
        ap[r] = agg + (size_t)(row < nNodes ? row : nNodes - 1) * D;
    }

    float4 acc[8];
    #pragma unroll
    for (int r = 0; r < 8; ++r)
        acc[r] = make_float4(bs[c], bs[c + 1], bs[c + 2], bs[c + 3]);

    for (int k = 0; k < D; k += 4) {
        float4 w0 = *(const float4*)&Ws[(k + 0) * D + c];
        float4 w1 = *(const float4*)&Ws[(k + 1) * D + c];
        float4 w2 = *(const float4*)&Ws[(k + 2) * D + c];
        float4 w3 = *(const float4*)&Ws[(k + 3) * D + c];
        #pragma unroll
        for (int r = 0; r < 8; ++r) {
            float4 a = *(const float4*)(ap[r] + k);
            acc[r].x += a.x * w0.x + a.y * w1.x + a.z * w2.x + a.w * w3.x;
            acc[r].y += a.x * w0.y + a.y * w1.y + a.z * w2.y + a.w * w3.y;
            acc[r].z += a.x * w0.z + a.y * w1.z + a.z * w2.z + a.w * w3.z;
            acc[r].w += a.x * w0.w + a.y * w1.w + a.z * w2.w + a.w * w3.w;
        }
    }

    #pragma unroll
    for (int r = 0; r < 8; ++r) {
        int row = row0 + r;
        if (row >= nNodes) break;
        if (xf32) {
            ((float4*)outv)[(size_t)row * 32 + cg] = acc[r];
        } else {
            ushort4 o;
            o.x = f2bf(acc[r].x); o.y = f2bf(acc[r].y);
            o.z = f2bf(acc[r].z); o.w = f2bf(acc[r].w);
            ((ushort4*)outv)[(size_t)row * 32 + cg] = o;
        }
    }
}

static inline size_t alignup(size_t v, size_t a) { return (v + a - 1) & ~(a - 1); }

extern "C" void kernel_launch(void* const* d_in, const int* in_sizes, int n_in,
                              void* d_out, int out_size, void* d_ws, size_t ws_size,
                              hipStream_t stream) {
    const void* x  = d_in[0];
    const void* ei = d_in[1];
    const void* W  = d_in[2];
    const void* b  = d_in[3];

    const int nNodes = in_sizes[0] / D;
    const int nEdges = in_sizes[1] / 2;

    // ws layout: flags | partials[1024] | starts[N+1] | cursors[N] | bucket[E] | agg[N*D]
    size_t off_part    = 512;
    size_t off_starts  = off_part + 4096;
    size_t off_cursors = alignup(off_starts + 4ull * (nNodes + 1), 256);
    size_t off_bucket  = alignup(off_cursors + 4ull * nNodes, 256);
    size_t off_agg     = alignup(off_bucket + 4ull * nEdges, 512);
    size_t need_fast   = off_agg + (size_t)nNodes * D * sizeof(float);

    int* flags = (int*)d_ws;
    probe_kernel<<<1, 64, 0, stream>>>((const unsigned short*)x, (const long long*)ei,
                                       nNodes, flags);

    const int eblocks = (nEdges + 255) / 256;

    if (ws_size >= need_fast) {
        int*   partials = (int*)((char*)d_ws + off_part);
        int*   starts   = (int*)((char*)d_ws + off_starts);
        int*   cursors  = (int*)((char*)d_ws + off_cursors);
        int*   bucket   = (int*)((char*)d_ws + off_bucket);
        float* agg      = (float*)((char*)d_ws + off_agg);

        hipMemsetAsync(cursors, 0, 4ull * nNodes, stream);  // counts first live here
        count_kernel<<<eblocks, 256, 0, stream>>>(ei, cursors, nEdges, flags);

        const int nb = (nNodes + 1023) / 1024;   // <= 1024 for N <= 1M
        scanA_kernel<<<nb, 256, 0, stream>>>(cursors, partials, nNodes);
        scanB_kernel<<<1, 1024, 0, stream>>>(partials, nb);
        scanC_kernel<<<nb, 256, 0, stream>>>(cursors, partials, starts, cursors,
                                             nNodes, nEdges);

        fill_kernel<<<eblocks, 256, 0, stream>>>(ei, cursors, bucket, nEdges, flags);

        int gblocks = (nNodes + 3) / 4;          // 4 waves/block, 1 wave/node
        gather_kernel<<<gblocks, 256, 0, stream>>>(x, starts, bucket, agg, nNodes, flags);

        int mblocks = (nNodes + 63) / 64;
        gemm_kernel<<<mblocks, 256, 0, stream>>>(agg, W, b, d_out, nNodes, flags);
    } else {
        float* agg = (float*)((char*)d_ws + 512);
        hipMemsetAsync(agg, 0, (size_t)nNodes * D * sizeof(float), stream);
        long long total = (long long)nEdges * 32;
        int sblocks = (int)((total + 255) / 256);
        scatter_kernel<<<sblocks, 256, 0, stream>>>(x, ei, agg, nEdges, flags);
        int mblocks = (nNodes + 63) / 64;
        gemm_kernel<<<mblocks, 256, 0, stream>>>(agg, W, b, d_out, nNodes, flags);
    }
}

// Round 5
// 409.057 us; speedup vs baseline: 7.7635x; 1.1687x over previous
//
#include <hip/hip_runtime.h>
#include <hip/hip_bf16.h>

#define D 128

__device__ __forceinline__ float bf2f(unsigned short u) {
    union { unsigned int i; float f; } c;
    c.i = ((unsigned int)u) << 16;
    return c.f;
}
__device__ __forceinline__ float bits2f(unsigned int i) {
    union { unsigned int i; float f; } c;
    c.i = i;
    return c.f;
}
__device__ __forceinline__ unsigned short f2bf(float f) {
    __hip_bfloat16 h = __float2bfloat16(f);
    return *(unsigned short*)&h;
}

// Probe dtypes at runtime (one wave). flags[0]=1 if x is fp32; flags[1]=1 if ei is int64.
__global__ __launch_bounds__(64) void probe_kernel(
    const unsigned short* __restrict__ x,
    const long long* __restrict__ ei64,
    int nNodes, int* __restrict__ flags)
{
    const int lane = threadIdx.x;
    int cnt = 0;
    for (int i = lane; i < 512; i += 64) {
        float v = bf2f(x[i]);
        if (!(fabsf(v) < 1e4f)) cnt++;   // NaN counts
    }
    unsigned long long m1 = __ballot(cnt > 0);
    long long v = ei64[lane];
    int bad = (v < 0 || v >= (long long)nNodes) ? 1 : 0;
    unsigned long long m2 = __ballot(bad);
    if (lane == 0) {
        flags[0] = (__popcll(m1) > 2) ? 1 : 0;
        flags[1] = (m2 == 0) ? 1 : 0;
    }
}

// ---------- linked-list build: next[e] = atomicExch(head[slot][dst], e) ----------
// next[e] writes are coalesced (indexed by e); only head exchanges are random.
__global__ __launch_bounds__(256) void build_ll(
    const void* __restrict__ eiv, int* __restrict__ head, int* __restrict__ next,
    int nEdges, int nNodes, int K, const int* __restrict__ flags)
{
    int e = blockIdx.x * 256 + threadIdx.x;
    if (e >= nEdges) return;
    int d;
    if (flags[1]) d = (int)((const long long*)eiv)[(size_t)nEdges + e];
    else          d = ((const int*)eiv)[(size_t)nEdges + e];
    int slot = e & (K - 1);
    next[e] = atomicExch(&head[(size_t)slot * nNodes + d], e);
}

// ---------- gather: one wave per node, walk K chains concurrently (MLP) ----------
__global__ __launch_bounds__(256) void gather_ll(
    const void* __restrict__ xv, const int* __restrict__ head,
    const int* __restrict__ next, const void* __restrict__ eiv,
    float* __restrict__ agg, int nNodes, int nEdges, int K,
    const int* __restrict__ flags)
{
    int node = blockIdx.x * 4 + (threadIdx.x >> 6);
    if (node >= nNodes) return;
    const int lane = threadIdx.x & 63;
    const int xf32 = flags[0];
    const int i64  = flags[1];

    int cur[4];
    #pragma unroll
    for (int c = 0; c < 4; ++c)
        cur[c] = (c < K) ? head[(size_t)c * nNodes + node] : -1;

    float ax[4] = {0.f, 0.f, 0.f, 0.f};
    float ay[4] = {0.f, 0.f, 0.f, 0.f};

    const long long* ei64 = (const long long*)eiv;
    const int*       ei32 = (const int*)eiv;
    const float2*       x2 = (const float2*)xv;
    const unsigned int* xu = (const unsigned int*)xv;

    for (;;) {
        bool any = false;
        int nx[4], s[4];
        #pragma unroll
        for (int c = 0; c < 4; ++c) {
            if (cur[c] >= 0) {
                nx[c] = next[cur[c]];
                s[c]  = i64 ? (int)ei64[cur[c]] : ei32[cur[c]];
                any = true;
            }
        }
        if (!any) break;
        #pragma unroll
        for (int c = 0; c < 4; ++c) {
            if (cur[c] >= 0) {
                if (xf32) {
                    float2 v = x2[(size_t)s[c] * 64 + lane];
                    ax[c] += v.x; ay[c] += v.y;
                } else {
                    unsigned int u = xu[(size_t)s[c] * 64 + lane];
                    ax[c] += bits2f(u << 16);
                    ay[c] += bits2f(u & 0xFFFF0000u);
                }
                cur[c] = nx[c];
            }
        }
    }

    float2 o;
    o.x = (ax[0] + ax[1]) + (ax[2] + ax[3]);
    o.y = (ay[0] + ay[1]) + (ay[2] + ay[3]);
    ((float2*)agg)[(size_t)node * 64 + lane] = o;
}

// ---------- fallback scatter (atomics) if ws too small ----------
__global__ __launch_bounds__(256) void scatter_kernel(
    const void* __restrict__ xv, const void* __restrict__ eiv,
    float* __restrict__ agg, int nEdges, const int* __restrict__ flags)
{
    long long tid = (long long)blockIdx.x * 256 + threadIdx.x;
    int e = (int)(tid >> 5);
    if (e >= nEdges) return;
    int q = (int)tid & 31;

    const int xf32 = flags[0];
    int s, d;
    if (flags[1]) {
        const long long* ei = (const long long*)eiv;
        s = (int)ei[e]; d = (int)ei[(size_t)nEdges + e];
    } else {
        const int* ei = (const int*)eiv;
        s = ei[e]; d = ei[(size_t)nEdges + e];
    }
    float4 v;
    if (xf32) {
        v = ((const float4*)xv)[(size_t)s * 32 + q];
    } else {
        ushort4 u = ((const ushort4*)xv)[(size_t)s * 32 + q];
        v.x = bf2f(u.x); v.y = bf2f(u.y); v.z = bf2f(u.z); v.w = bf2f(u.w);
    }
    float* ap = agg + (size_t)d * D + q * 4;
    atomicAdd(ap + 0, v.x);
    atomicAdd(ap + 1, v.y);
    atomicAdd(ap + 2, v.z);
    atomicAdd(ap + 3, v.w);
}

// ---------- register-blocked GEMM: out = cast(agg @ W + b) ----------
__global__ __launch_bounds__(256) void gemm_kernel(
    const float* __restrict__ agg, const void* __restrict__ Wv,
    const void* __restrict__ bv, void* __restrict__ outv,
    int nNodes, const int* __restrict__ flags)
{
    __shared__ float Ws[D * D];   // 64 KB
    __shared__ float bs[D];

    const int xf32 = flags[0];
    if (xf32) {
        const float* W = (const float*)Wv;
        for (int i = threadIdx.x; i < D * D; i += 256) Ws[i] = W[i];
        if (threadIdx.x < D) bs[threadIdx.x] = ((const float*)bv)[threadIdx.x];
    } else {
        const unsigned short* W = (const unsigned short*)Wv;
        for (int i = threadIdx.x; i < D * D; i += 256) Ws[i] = bf2f(W[i]);
        if (threadIdx.x < D) bs[threadIdx.x] = bf2f(((const unsigned short*)bv)[threadIdx.x]);
    }
    __syncthreads();

    const int cg = threadIdx.x & 31;   // col group (4 cols)
    const int rg = threadIdx.x >> 5;   // row group (8 rows)
    const int c = cg * 4;
    const int row0 = blockIdx.x * 64 + rg * 8;

    const float* ap[8];
    #pragma unroll
    for (int r = 0; r < 8; ++r) {
        int row = row0 + r;
        ap[r] = agg + (size_t)(row < nNodes ? row : nNodes - 1) * D;
    }

    float4 acc[8];
    #pragma unroll
    for (int r = 0; r < 8; ++r)
        acc[r] = make_float4(bs[c], bs[c + 1], bs[c + 2], bs[c + 3]);

    for (int k = 0; k < D; k += 4) {
        float4 w0 = *(const float4*)&Ws[(k + 0) * D + c];
        float4 w1 = *(const float4*)&Ws[(k + 1) * D + c];
        float4 w2 = *(const float4*)&Ws[(k + 2) * D + c];
        float4 w3 = *(const float4*)&Ws[(k + 3) * D + c];
        #pragma unroll
        for (int r = 0; r < 8; ++r) {
            float4 a = *(const float4*)(ap[r] + k);
            acc[r].x += a.x * w0.x + a.y * w1.x + a.z * w2.x + a.w * w3.x;
            acc[r].y += a.x * w0.y + a.y * w1.y + a.z * w2.y + a.w * w3.y;
            acc[r].z += a.x * w0.z + a.y * w1.z + a.z * w2.z + a.w * w3.z;
            acc[r].w += a.x * w0.w + a.y * w1.w + a.z * w2.w + a.w * w3.w;
        }
    }

    #pragma unroll
    for (int r = 0; r < 8; ++r) {
        int row = row0 + r;
        if (row >= nNodes) break;
        if (xf32) {
            ((float4*)outv)[(size_t)row * 32 + cg] = acc[r];
        } else {
            ushort4 o;
            o.x = f2bf(acc[r].x); o.y = f2bf(acc[r].y);
            o.z = f2bf(acc[r].z); o.w = f2bf(acc[r].w);
            ((ushort4*)outv)[(size_t)row * 32 + cg] = o;
        }
    }
}

static inline size_t alignup(size_t v, size_t a) { return (v + a - 1) & ~(a - 1); }

extern "C" void kernel_launch(void* const* d_in, const int* in_sizes, int n_in,
                              void* d_out, int out_size, void* d_ws, size_t ws_size,
                              hipStream_t stream) {
    const void* x  = d_in[0];
    const void* ei = d_in[1];
    const void* W  = d_in[2];
    const void* b  = d_in[3];

    const int nNodes = in_sizes[0] / D;
    const int nEdges = in_sizes[1] / 2;

    int* flags = (int*)d_ws;
    probe_kernel<<<1, 64, 0, stream>>>((const unsigned short*)x, (const long long*)ei,
                                       nNodes, flags);

    // pick largest K in {4,2,1} that fits:
    // ws layout: flags(512) | head[K*N] | next[E] | agg[N*D]
    int K = 0;
    size_t off_head = 512, off_next = 0, off_agg = 0;
    for (int k = 4; k >= 1; k >>= 1) {
        size_t onext = alignup(off_head + 4ull * k * nNodes, 256);
        size_t oagg  = alignup(onext + 4ull * nEdges, 512);
        size_t need  = oagg + (size_t)nNodes * D * sizeof(float);
        if (ws_size >= need) { K = k; off_next = onext; off_agg = oagg; break; }
    }

    const int eblocks = (nEdges + 255) / 256;

    if (K > 0) {
        int*   head = (int*)((char*)d_ws + off_head);
        int*   next = (int*)((char*)d_ws + off_next);
        float* agg  = (float*)((char*)d_ws + off_agg);

        hipMemsetAsync(head, 0xFF, 4ull * K * nNodes, stream);   // head = -1
        build_ll<<<eblocks, 256, 0, stream>>>(ei, head, next, nEdges, nNodes, K, flags);

        int gblocks = (nNodes + 3) / 4;   // 4 waves/block, 1 wave/node
        gather_ll<<<gblocks, 256, 0, stream>>>(x, head, next, ei, agg,
                                               nNodes, nEdges, K, flags);

        int mblocks = (nNodes + 63) / 64;
        gemm_kernel<<<mblocks, 256, 0, stream>>>(agg, W, b, d_out, nNodes, flags);
    } else {
        float* agg = (float*)((char*)d_ws + 512);
        hipMemsetAsync(agg, 0, (size_t)nNodes * D * sizeof(float), stream);
        long long total = (long long)nEdges * 32;
        int sblocks = (int)((total + 255) / 256);
        scatter_kernel<<<sblocks, 256, 0, stream>>>(x, ei, agg, nEdges, flags);
        int mblocks = (nNodes + 63) / 64;
        gemm_kernel<<<mblocks, 256, 0, stream>>>(agg, W, b, d_out, nNodes, flags);
    }
}

// Round 6
// 394.626 us; speedup vs baseline: 8.0474x; 1.0366x over previous
//
#include <hip/hip_runtime.h>
#include <hip/hip_bf16.h>

#define D 128

__device__ __forceinline__ float bf2f(unsigned short u) {
    union { unsigned int i; float f; } c;
    c.i = ((unsigned int)u) << 16;
    return c.f;
}
__device__ __forceinline__ float bits2f(unsigned int i) {
    union { unsigned int i; float f; } c;
    c.i = i;
    return c.f;
}
__device__ __forceinline__ unsigned short f2bf(float f) {
    __hip_bfloat16 h = __float2bfloat16(f);
    return *(unsigned short*)&h;
}

// Probe dtypes at runtime (one wave). flags[0]=1 if x is fp32; flags[1]=1 if ei is int64.
__global__ __launch_bounds__(64) void probe_kernel(
    const unsigned short* __restrict__ x,
    const long long* __restrict__ ei64,
    int nNodes, int* __restrict__ flags)
{
    const int lane = threadIdx.x;
    int cnt = 0;
    for (int i = lane; i < 512; i += 64) {
        float v = bf2f(x[i]);
        if (!(fabsf(v) < 1e4f)) cnt++;   // NaN counts
    }
    unsigned long long m1 = __ballot(cnt > 0);
    long long v = ei64[lane];
    int bad = (v < 0 || v >= (long long)nNodes) ? 1 : 0;
    unsigned long long m2 = __ballot(bad);
    if (lane == 0) {
        flags[0] = (__popcll(m1) > 2) ? 1 : 0;
        flags[1] = (m2 == 0) ? 1 : 0;
    }
}

// ---------- GEMM: out = in @ W (+ b). Register-blocked 64-row tiles. ----------
// in_f32 / out_f32: 1 = fp32, 0 = bf16, -1 = follow flags[0].
__global__ __launch_bounds__(256) void gemm_kernel(
    const void* __restrict__ inv, const void* __restrict__ Wv,
    const void* __restrict__ bv, void* __restrict__ outv,
    int nNodes, const int* __restrict__ flags,
    int in_f32p, int out_f32p, int add_bias)
{
    __shared__ float Ws[D * D];   // 64 KB
    __shared__ float bs[D];

    const int xf32 = flags[0];
    const int in_f32  = (in_f32p  < 0) ? xf32 : in_f32p;
    const int out_f32 = (out_f32p < 0) ? xf32 : out_f32p;

    if (xf32) {   // W/b dtype follows x dtype
        const float* W = (const float*)Wv;
        for (int i = threadIdx.x; i < D * D; i += 256) Ws[i] = W[i];
        if (threadIdx.x < D)
            bs[threadIdx.x] = add_bias ? ((const float*)bv)[threadIdx.x] : 0.f;
    } else {
        const unsigned short* W = (const unsigned short*)Wv;
        for (int i = threadIdx.x; i < D * D; i += 256) Ws[i] = bf2f(W[i]);
        if (threadIdx.x < D)
            bs[threadIdx.x] = add_bias ? bf2f(((const unsigned short*)bv)[threadIdx.x]) : 0.f;
    }
    __syncthreads();

    const int cg = threadIdx.x & 31;   // col group (4 cols)
    const int rg = threadIdx.x >> 5;   // row group (8 rows)
    const int c = cg * 4;
    const int row0 = blockIdx.x * 64 + rg * 8;

    size_t rIdx[8];
    #pragma unroll
    for (int r = 0; r < 8; ++r) {
        int row = row0 + r;
        rIdx[r] = (size_t)(row < nNodes ? row : nNodes - 1);
    }

    float4 acc[8];
    #pragma unroll
    for (int r = 0; r < 8; ++r)
        acc[r] = make_float4(bs[c], bs[c + 1], bs[c + 2], bs[c + 3]);

    if (in_f32) {
        const float* in = (const float*)inv;
        for (int k = 0; k < D; k += 4) {
            float4 w0 = *(const float4*)&Ws[(k + 0) * D + c];
            float4 w1 = *(const float4*)&Ws[(k + 1) * D + c];
            float4 w2 = *(const float4*)&Ws[(k + 2) * D + c];
            float4 w3 = *(const float4*)&Ws[(k + 3) * D + c];
            #pragma unroll
            for (int r = 0; r < 8; ++r) {
                float4 a = *(const float4*)(in + rIdx[r] * D + k);
                acc[r].x += a.x * w0.x + a.y * w1.x + a.z * w2.x + a.w * w3.x;
                acc[r].y += a.x * w0.y + a.y * w1.y + a.z * w2.y + a.w * w3.y;
                acc[r].z += a.x * w0.z + a.y * w1.z + a.z * w2.z + a.w * w3.z;
                acc[r].w += a.x * w0.w + a.y * w1.w + a.z * w2.w + a.w * w3.w;
            }
        }
    } else {
        const unsigned short* in = (const unsigned short*)inv;
        for (int k = 0; k < D; k += 4) {
            float4 w0 = *(const float4*)&Ws[(k + 0) * D + c];
            float4 w1 = *(const float4*)&Ws[(k + 1) * D + c];
            float4 w2 = *(const float4*)&Ws[(k + 2) * D + c];
            float4 w3 = *(const float4*)&Ws[(k + 3) * D + c];
            #pragma unroll
            for (int r = 0; r < 8; ++r) {
                ushort4 u = *(const ushort4*)(in + rIdx[r] * D + k);
                float ax = bf2f(u.x), ay = bf2f(u.y), az = bf2f(u.z), aw = bf2f(u.w);
                acc[r].x += ax * w0.x + ay * w1.x + az * w2.x + aw * w3.x;
                acc[r].y += ax * w0.y + ay * w1.y + az * w2.y + aw * w3.y;
                acc[r].z += ax * w0.z + ay * w1.z + az * w2.z + aw * w3.z;
                acc[r].w += ax * w0.w + ay * w1.w + az * w2.w + aw * w3.w;
            }
        }
    }

    #pragma unroll
    for (int r = 0; r < 8; ++r) {
        int row = row0 + r;
        if (row >= nNodes) break;
        if (out_f32) {
            ((float4*)outv)[(size_t)row * 32 + cg] = acc[r];
        } else {
            ushort4 o;
            o.x = f2bf(acc[r].x); o.y = f2bf(acc[r].y);
            o.z = f2bf(acc[r].z); o.w = f2bf(acc[r].w);
            ((ushort4*)outv)[(size_t)row * 32 + cg] = o;
        }
    }
}

// ---------- linked-list build: next2[e] = {atomicExch(head[slot][dst], e), src} ----------
__global__ __launch_bounds__(256) void build_ll(
    const void* __restrict__ eiv, int* __restrict__ head, int2* __restrict__ next2,
    int nEdges, int nNodes, int K, const int* __restrict__ flags)
{
    int e = blockIdx.x * 256 + threadIdx.x;
    if (e >= nEdges) return;
    int s, d;
    if (flags[1]) {
        const long long* ei = (const long long*)eiv;
        s = (int)ei[e];
        d = (int)ei[(size_t)nEdges + e];
    } else {
        const int* ei = (const int*)eiv;
        s = ei[e];
        d = ei[(size_t)nEdges + e];
    }
    int slot = e & (K - 1);
    int old = atomicExch(&head[(size_t)slot * nNodes + d], e);
    next2[e] = make_int2(old, s);
}

// ---------- gather y-rows via K chains, fuse bias + output cast ----------
__global__ __launch_bounds__(256) void gather_y(
    const unsigned int* __restrict__ yu,   // y as bf16 pairs (N x 64 uints)
    const int* __restrict__ head, const int2* __restrict__ next2,
    const void* __restrict__ bv, void* __restrict__ outv,
    int nNodes, int K, const int* __restrict__ flags)
{
    int node = blockIdx.x * 4 + (threadIdx.x >> 6);
    if (node >= nNodes) return;
    const int lane = threadIdx.x & 63;
    const int xf32 = flags[0];
    const int nodeU = __builtin_amdgcn_readfirstlane(node);

    int cur[4];
    #pragma unroll
    for (int c = 0; c < 4; ++c)
        cur[c] = (c < K) ? __builtin_amdgcn_readfirstlane(head[(size_t)c * nNodes + nodeU])
                         : -1;

    float ax[4] = {0.f, 0.f, 0.f, 0.f};
    float ay[4] = {0.f, 0.f, 0.f, 0.f};

    for (;;) {
        bool any = false;
        int nx[4], s[4];
        #pragma unroll
        for (int c = 0; c < 4; ++c) {
            if (cur[c] >= 0) {
                int2 t = next2[cur[c]];
                nx[c] = __builtin_amdgcn_readfirstlane(t.x);
                s[c]  = __builtin_amdgcn_readfirstlane(t.y);
                any = true;
            }
        }
        if (!any) break;
        #pragma unroll
        for (int c = 0; c < 4; ++c) {
            if (cur[c] >= 0) {
                unsigned int u = yu[(size_t)s[c] * 64 + lane];
                ax[c] += bits2f(u << 16);
                ay[c] += bits2f(u & 0xFFFF0000u);
                cur[c] = nx[c];
            }
        }
    }

    float ox = (ax[0] + ax[1]) + (ax[2] + ax[3]);
    float oy = (ay[0] + ay[1]) + (ay[2] + ay[3]);

    if (xf32) {
        float2 bb = ((const float2*)bv)[lane];
        float2 o; o.x = ox + bb.x; o.y = oy + bb.y;
        ((float2*)outv)[(size_t)node * 64 + lane] = o;
    } else {
        unsigned int ub = ((const unsigned int*)bv)[lane];
        ox += bits2f(ub << 16);
        oy += bits2f(ub & 0xFFFF0000u);
        unsigned int o = ((unsigned int)f2bf(ox)) | (((unsigned int)f2bf(oy)) << 16);
        ((unsigned int*)outv)[(size_t)node * 64 + lane] = o;
    }
}

// ---------- fallback scatter (atomics) if ws too small ----------
__global__ __launch_bounds__(256) void scatter_kernel(
    const void* __restrict__ xv, const void* __restrict__ eiv,
    float* __restrict__ agg, int nEdges, const int* __restrict__ flags)
{
    long long tid = (long long)blockIdx.x * 256 + threadIdx.x;
    int e = (int)(tid >> 5);
    if (e >= nEdges) return;
    int q = (int)tid & 31;

    const int xf32 = flags[0];
    int s, d;
    if (flags[1]) {
        const long long* ei = (const long long*)eiv;
        s = (int)ei[e]; d = (int)ei[(size_t)nEdges + e];
    } else {
        const int* ei = (const int*)eiv;
        s = ei[e]; d = ei[(size_t)nEdges + e];
    }
    float4 v;
    if (xf32) {
        v = ((const float4*)xv)[(size_t)s * 32 + q];
    } else {
        ushort4 u = ((const ushort4*)xv)[(size_t)s * 32 + q];
        v.x = bf2f(u.x); v.y = bf2f(u.y); v.z = bf2f(u.z); v.w = bf2f(u.w);
    }
    float* ap = agg + (size_t)d * D + q * 4;
    atomicAdd(ap + 0, v.x);
    atomicAdd(ap + 1, v.y);
    atomicAdd(ap + 2, v.z);
    atomicAdd(ap + 3, v.w);
}

static inline size_t alignup(size_t v, size_t a) { return (v + a - 1) & ~(a - 1); }

extern "C" void kernel_launch(void* const* d_in, const int* in_sizes, int n_in,
                              void* d_out, int out_size, void* d_ws, size_t ws_size,
                              hipStream_t stream) {
    const void* x  = d_in[0];
    const void* ei = d_in[1];
    const void* W  = d_in[2];
    const void* b  = d_in[3];

    const int nNodes = in_sizes[0] / D;
    const int nEdges = in_sizes[1] / 2;

    int* flags = (int*)d_ws;
    probe_kernel<<<1, 64, 0, stream>>>((const unsigned short*)x, (const long long*)ei,
                                       nNodes, flags);

    // fast path ws layout: flags(512) | head[K*N] | next2[E] (int2) | y[N*D] (bf16)
    int K = 0;
    size_t off_head = 512, off_next = 0, off_y = 0;
    for (int k = 4; k >= 1; k >>= 1) {
        size_t onext = alignup(off_head + 4ull * k * nNodes, 256);
        size_t oy    = alignup(onext + 8ull * nEdges, 512);
        size_t need  = oy + (size_t)nNodes * D * 2;   // y bf16
        if (ws_size >= need) { K = k; off_next = onext; off_y = oy; break; }
    }

    const int eblocks = (nEdges + 255) / 256;
    const int mblocks = (nNodes + 63) / 64;

    if (K > 0) {
        int*  head  = (int*)((char*)d_ws + off_head);
        int2* next2 = (int2*)((char*)d_ws + off_next);
        void* y     = (void*)((char*)d_ws + off_y);

        // y = x @ W   (no bias; y stored bf16)
        gemm_kernel<<<mblocks, 256, 0, stream>>>(x, W, b, y, nNodes, flags,
                                                 /*in_f32*/-1, /*out_f32*/0, /*bias*/0);

        hipMemsetAsync(head, 0xFF, 4ull * K * nNodes, stream);   // head = -1
        build_ll<<<eblocks, 256, 0, stream>>>(ei, head, next2, nEdges, nNodes, K, flags);

        int gblocks = (nNodes + 3) / 4;   // 1 wave/node, 4 waves/block
        gather_y<<<gblocks, 256, 0, stream>>>((const unsigned int*)y, head, next2,
                                              b, d_out, nNodes, K, flags);
    } else {
        // fallback: atomic scatter into fp32 agg, then out = agg @ W + b
        float* agg = (float*)((char*)d_ws + 512);
        hipMemsetAsync(agg, 0, (size_t)nNodes * D * sizeof(float), stream);
        long long total = (long long)nEdges * 32;
        int sblocks = (int)((total + 255) / 256);
        scatter_kernel<<<sblocks, 256, 0, stream>>>(x, ei, agg, nEdges, flags);
        gemm_kernel<<<mblocks, 256, 0, stream>>>(agg, W, b, d_out, nNodes, flags,
                                                 /*in_f32*/1, /*out_f32*/-1, /*bias*/1);
    }
}